// Round 10
// baseline (98.761 us; speedup 1.0000x reference)
//
#include <hip/hip_runtime.h>
#include <math.h>

// KDE via GEMM trick, v10: acc-pipelined epilogue + 4-deep B prefetch.
//   density[i] = (1/M) * sum_j exp2(-C2*sq_ij - log2(M))
//   sq_ij = |x_i|^2 + |d_j|^2 - 2*dot(x_i,d_j)
//
// ROUND-9 FINDINGS: (a) the ~50 us total-vs-main gap is the harness's
// unconditional 256 MiB 0xAA ws-poison fill (~43 us/replay, visible as
// fillBufferAligned in top-5) — unavoidable; controllable budget is
// prep (~4 us) + main (~39 us). (b) main is stall-bound: per-tile serial
// chain load->4xMFMA->epilogue with prefetch depth 1; both pipes <30%.
//
// v10: wave = 16 rows (af = 16 VGPR). Per 16-col tile: 4-MFMA chain.
// PIPELINED: epilogue of tile t-1 runs while tile t's MFMA is in flight
// (accE/accO alternate; first epilogue neutralized by dPrev=-inf ->
// exp2(-inf)=0, no branch). B prefetch 4 tiles deep via NAMED buffers
// b0..b3, outer loop rolled (16 bodies x 4 tiles), constant indices only,
// amdgpu_waves_per_eu(4,4) pins the 128-reg budget (~110 live, no spill
// -- r7/r8/r9 lessons). Tile index wrap masked &63 (in-group, in-bounds).
// Block = 4 waves = 64 rows x 1024 cols; grid = 128x8 = 1024 blocks =
// exactly 4 blocks/CU, one generation. All 4 waves walk the same col
// sequence -> B reads L1-dedup across waves. No LDS, no barriers.
//
// Fragment mappings (verified end-to-end rounds 2-9):
//   A: lane holds A[m=lane&15][k=(lane>>4)*8+j]
//   B: lane holds B^T row-major: col=lane&15, k=(lane>>4)*8+j
//   C/D: col=lane&15, row=(lane>>4)*4+reg
// fp16 single-pass accuracy verified r4-r9: absmax 2.8e-17 vs 2.4e-16 thr.

#define D_DIM 128
#define TPG   64   // 16-col tiles per col-group (1024 cols) — compile-time

typedef _Float16 f16x8 __attribute__((ext_vector_type(8)));
typedef _Float16 f16x4 __attribute__((ext_vector_type(4)));
typedef __attribute__((ext_vector_type(4))) float f32x4;

#define C2F ((float)(0.5 / 2.50662827463100050242 * 1.44269504088896340736))

// ---- prep: fp32 -> fp16 fragment-major + pre-scaled norms ----------------
// Thread (row, seg 0..31): k = seg*4 -> kc=seg>>3, q=(seg>>1)&3, j0=(seg&1)*4;
// 8 B store at halves offset ((t*4+kc)*64 + q*16 + r)*8 + j0.
__global__ __launch_bounds__(256)
void prep_kernel(const float* __restrict__ x, const float* __restrict__ data,
                 _Float16* __restrict__ xf, _Float16* __restrict__ df,
                 float* __restrict__ xn_u, float* __restrict__ dn_s,
                 int xThreads, float negLogM) {
    const int gid = blockIdx.x * 256 + threadIdx.x;
    const int which = (gid >= xThreads);
    const int id = which ? (gid - xThreads) : gid;
    const int row = id >> 5, seg = id & 31;
    const float* src = which ? data : x;
    _Float16* dst = which ? df : xf;

    const float4 v = *(const float4*)&src[(size_t)row * D_DIM + seg * 4];

    const int t = row >> 4, r = row & 15;
    const int kc = seg >> 3, q = (seg >> 1) & 3, j0 = (seg & 1) * 4;
    f16x4 h;
    h[0] = (_Float16)v.x; h[1] = (_Float16)v.y;
    h[2] = (_Float16)v.z; h[3] = (_Float16)v.w;
    *(f16x4*)&dst[((size_t)(t * 4 + kc) * 64 + q * 16 + r) * 8 + j0] = h;

    float nrm = fmaf(v.x, v.x, fmaf(v.y, v.y, fmaf(v.z, v.z, v.w * v.w)));
#pragma unroll
    for (int off = 1; off < 32; off <<= 1) nrm += __shfl_xor(nrm, off, 64);
    if (seg == 0) {
        if (which) dn_s[row] = -C2F * nrm;
        else       xn_u[row] = fmaf(-C2F, nrm, negLogM);
    }
}

// ---- main: 4 waves x 16 rows, pipelined, LDS/barrier-free ----------------
__global__ __launch_bounds__(256)
__attribute__((amdgpu_waves_per_eu(4, 4)))
void kde_f16v10(const _Float16* __restrict__ xf, const _Float16* __restrict__ df,
                const float* __restrict__ xn_u, const float* __restrict__ dn_s,
                float* __restrict__ out, int colGroups) {
    const int tid  = threadIdx.x;
    const int lane = tid & 63;
    const int w    = tid >> 6;
    const int q    = lane >> 4;
    const int r    = lane & 15;

    const int bid = blockIdx.x;
    const int cg  = bid % colGroups;
    const int rb  = bid / colGroups;
    const int rowBase  = rb * 64 + w * 16;   // this wave's 16 rows
    const int colTile0 = cg * TPG;

    const float twoC2 = 2.0f * C2F;

    // A fragments: 4 coalesced dwordx4 loads, once.
    const int tG = rb * 4 + w;
    f16x8 af[4];
#pragma unroll
    for (int kc = 0; kc < 4; ++kc)
        af[kc] = *(const f16x8*)&xf[((size_t)(tG * 4 + kc) * 64 + lane) * 8];

    const f32x4 u = *(const f32x4*)&xn_u[rowBase + q * 4];

    f32x4 srow = (f32x4){0.f, 0.f, 0.f, 0.f};

    const _Float16* dbase = &df[(size_t)colTile0 * 2048];  // 2048 halves/tile
    const float*    nbase = &dn_s[colTile0 * 16 + r];

    // Named 4-deep prefetch buffers (constant indices only).
    f16x8 b0[4], b1[4], b2[4], b3[4];
    float dv0, dv1, dv2, dv3;
#pragma unroll
    for (int kc = 0; kc < 4; ++kc) {
        b0[kc] = *(const f16x8*)&dbase[(size_t)0 * 2048 + ((size_t)kc * 64 + lane) * 8];
        b1[kc] = *(const f16x8*)&dbase[(size_t)1 * 2048 + ((size_t)kc * 64 + lane) * 8];
        b2[kc] = *(const f16x8*)&dbase[(size_t)2 * 2048 + ((size_t)kc * 64 + lane) * 8];
        b3[kc] = *(const f16x8*)&dbase[(size_t)3 * 2048 + ((size_t)kc * 64 + lane) * 8];
    }
    dv0 = nbase[0 * 16]; dv1 = nbase[1 * 16]; dv2 = nbase[2 * 16]; dv3 = nbase[3 * 16];

    // Pipelined accumulators: epilogue of tile t-1 overlaps MFMA of tile t.
    // First epilogue neutralized: exp2(x + (-inf)) = 0.
    f32x4 accE = (f32x4){0.f, 0.f, 0.f, 0.f};
    f32x4 accO = (f32x4){0.f, 0.f, 0.f, 0.f};
    float dPrev = -INFINITY;   // accO is the "previous" at loop entry (zeros)

#define EPILOG(ACC, DV)                                                      \
    srow[0] += __builtin_amdgcn_exp2f(fmaf(twoC2, (ACC)[0], u[0] + (DV)));   \
    srow[1] += __builtin_amdgcn_exp2f(fmaf(twoC2, (ACC)[1], u[1] + (DV)));   \
    srow[2] += __builtin_amdgcn_exp2f(fmaf(twoC2, (ACC)[2], u[2] + (DV)));   \
    srow[3] += __builtin_amdgcn_exp2f(fmaf(twoC2, (ACC)[3], u[3] + (DV)))

#define MFMA4(ACC, B)                                                        \
    (ACC) = (f32x4){0.f, 0.f, 0.f, 0.f};                                     \
    _Pragma("unroll")                                                        \
    for (int kc = 0; kc < 4; ++kc)                                           \
        (ACC) = __builtin_amdgcn_mfma_f32_16x16x32_f16(af[kc], (B)[kc], (ACC), 0, 0, 0)

#pragma unroll 1
    for (int it = 0; it < TPG; it += 4) {
        // tile it (even slot): MFMA -> accE; epilogue of previous (accO).
        MFMA4(accE, b0);
        EPILOG(accO, dPrev);
        dPrev = dv0;
        // tile it+1 (odd slot): MFMA -> accO; epilogue accE.
        MFMA4(accO, b1);
        EPILOG(accE, dPrev);
        dPrev = dv1;
        // reload b0,b1 <- tiles it+4, it+5 (masked: stays in-group)
        {
            const int t4 = (it + 4) & (TPG - 1), t5 = (it + 5) & (TPG - 1);
#pragma unroll
            for (int kc = 0; kc < 4; ++kc) {
                b0[kc] = *(const f16x8*)&dbase[(size_t)t4 * 2048 + ((size_t)kc * 64 + lane) * 8];
                b1[kc] = *(const f16x8*)&dbase[(size_t)t5 * 2048 + ((size_t)kc * 64 + lane) * 8];
            }
            dv0 = nbase[t4 * 16]; dv1 = nbase[t5 * 16];
        }
        // tile it+2: MFMA -> accE; epilogue accO.
        MFMA4(accE, b2);
        EPILOG(accO, dPrev);
        dPrev = dv2;
        // tile it+3: MFMA -> accO; epilogue accE.
        MFMA4(accO, b3);
        EPILOG(accE, dPrev);
        dPrev = dv3;
        // reload b2,b3 <- tiles it+6, it+7 (masked)
        {
            const int t6 = (it + 6) & (TPG - 1), t7 = (it + 7) & (TPG - 1);
#pragma unroll
            for (int kc = 0; kc < 4; ++kc) {
                b2[kc] = *(const f16x8*)&dbase[(size_t)t6 * 2048 + ((size_t)kc * 64 + lane) * 8];
                b3[kc] = *(const f16x8*)&dbase[(size_t)t7 * 2048 + ((size_t)kc * 64 + lane) * 8];
            }
            dv2 = nbase[t6 * 16]; dv3 = nbase[t7 * 16];
        }
    }
    // Final epilogue: last tile's acc is in accO.
    EPILOG(accO, dPrev);

#undef MFMA4
#undef EPILOG

    // Reduce srow over the 16 col-lanes (r) and accumulate to out.
#pragma unroll
    for (int p = 0; p < 4; ++p) {
        float s = srow[p];
        s += __shfl_xor(s, 1, 64);
        s += __shfl_xor(s, 2, 64);
        s += __shfl_xor(s, 4, 64);
        s += __shfl_xor(s, 8, 64);
        if (r == 0)
            atomicAdd(&out[rowBase + q * 4 + p], s);
    }
}

// ---------------- fallback: round-1 VALU kernel (any size, no ws) ---------
#define BN 128
#define BM 128
#define KT 32
#define LDSS 132

__global__ __launch_bounds__(256, 4)
void kde_valu(const float* __restrict__ x, const float* __restrict__ data,
              float* __restrict__ out, int N, int M) {
    __shared__ float xs[KT][LDSS];
    __shared__ float dsh[KT][LDSS];
    __shared__ float xn_s[BN];
    __shared__ float dn_s[BM];
    const int tid = threadIdx.x;
    const int ty = tid >> 4, tx = tid & 15;
    const int rowBase = blockIdx.y * BN, colBase = blockIdx.x * BM;
    float acc[8][8];
#pragma unroll
    for (int i = 0; i < 8; ++i)
#pragma unroll
        for (int j = 0; j < 8; ++j) acc[i][j] = 0.0f;
    float normAcc = 0.0f;
    for (int kc = 0; kc < D_DIM; kc += KT) {
        __syncthreads();
#pragma unroll
        for (int i = 0; i < 4; ++i) {
            const int idx = tid + i * 256;
            const int row = idx >> 3, kq = idx & 7;
            const float4 v = *(const float4*)&x[(size_t)(rowBase + row) * D_DIM + kc + kq * 4];
            xs[kq * 4 + 0][row] = v.x; xs[kq * 4 + 1][row] = v.y;
            xs[kq * 4 + 2][row] = v.z; xs[kq * 4 + 3][row] = v.w;
            const float4 wv = *(const float4*)&data[(size_t)(colBase + row) * D_DIM + kc + kq * 4];
            dsh[kq * 4 + 0][row] = wv.x; dsh[kq * 4 + 1][row] = wv.y;
            dsh[kq * 4 + 2][row] = wv.z; dsh[kq * 4 + 3][row] = wv.w;
        }
        __syncthreads();
        {
            const float* col = (tid < 128) ? &xs[0][tid] : &dsh[0][tid - 128];
#pragma unroll
            for (int k = 0; k < KT; ++k) { const float v = col[k * LDSS]; normAcc = fmaf(v, v, normAcc); }
        }
#pragma unroll
        for (int k = 0; k < KT; ++k) {
            float a[8], b[8];
            *(float4*)&a[0] = *(const float4*)&xs[k][ty * 8];
            *(float4*)&a[4] = *(const float4*)&xs[k][ty * 8 + 4];
            *(float4*)&b[0] = *(const float4*)&dsh[k][tx * 4];
            *(float4*)&b[4] = *(const float4*)&dsh[k][64 + tx * 4];
#pragma unroll
            for (int i = 0; i < 8; ++i)
#pragma unroll
                for (int j = 0; j < 8; ++j) acc[i][j] = fmaf(a[i], b[j], acc[i][j]);
        }
    }
    if (tid < 128) xn_s[tid] = normAcc; else dn_s[tid - 128] = normAcc;
    __syncthreads();
    const float C2 = C2F;
    const float negLogM = -log2f((float)M);
#pragma unroll
    for (int i = 0; i < 8; ++i) {
        const int row = ty * 8 + i;
        const float xnr = xn_s[row];
        float s = 0.0f;
#pragma unroll
        for (int j = 0; j < 8; ++j) {
            const int col = (j < 4) ? (tx * 4 + j) : (64 + tx * 4 + (j - 4));
            const float sq = xnr + dn_s[col] - 2.0f * acc[i][j];
            s += exp2f(fmaf(-C2, sq, negLogM));
        }
#pragma unroll
        for (int off = 1; off < 16; off <<= 1) s += __shfl_xor(s, off, 64);
        if (tx == 0) atomicAdd(&out[rowBase + row], s);
    }
}

extern "C" void kernel_launch(void* const* d_in, const int* in_sizes, int n_in,
                              void* d_out, int out_size, void* d_ws, size_t ws_size,
                              hipStream_t stream) {
    const float* x    = (const float*)d_in[0];
    const float* data = (const float*)d_in[1];
    float* out = (float*)d_out;
    const int N = in_sizes[0] / D_DIM;
    const int M = in_sizes[1] / D_DIM;

    hipMemsetAsync(d_out, 0, (size_t)out_size * sizeof(float), stream);

    const size_t need = (size_t)(N + M) * D_DIM * 2 + (size_t)(N + M) * 4;
    if (ws_size < need || (N & 63) || (M & 1023)) {
        dim3 grid(M / BM, N / BN);
        kde_valu<<<grid, 256, 0, stream>>>(x, data, out, N, M);
        return;
    }

    _Float16* xf = (_Float16*)d_ws;
    _Float16* df = xf + (size_t)N * D_DIM;
    float* xn_u = (float*)(df + (size_t)M * D_DIM);
    float* dn_s = xn_u + N;

    const float negLogM = -log2f((float)M);
    const int xThreads = N * 32;
    const int totThreads = (N + M) * 32;
    prep_kernel<<<totThreads / 256, 256, 0, stream>>>(x, data, xf, df, xn_u, dn_s,
                                                      xThreads, negLogM);

    const int colGroups = M / 1024;          // 1024 cols/group, TPG=64 tiles
    const int rowBlocks = N / 64;
    kde_f16v10<<<rowBlocks * colGroups, 256, 0, stream>>>(xf, df, xn_u, dn_s, out,
                                                          colGroups);
}

// Round 11
// 95.569 us; speedup vs baseline: 1.0334x; 1.0334x over previous
//
#include <hip/hip_runtime.h>
#include <math.h>

// KDE via GEMM trick, v11: 64 rows/wave — VMEM-bandwidth-first design.
//   density[i] = (1/M) * sum_j exp2(-C2*sq_ij - log2(M))
//   sq_ij = |x_i|^2 + |d_j|^2 - 2*dot(x_i,d_j)
//
// ROUND-10 ANALYSIS: v9/v10 both plateau ~40 us because per-CU L1/TA
// bandwidth is the floor: every B-fragment dwordx4 moves 1 KB/wave-instr
// through ~64 B/cyc per CU regardless of hit/miss. B-bytes per output
// pair = 4096/(rowsPerWave*16). v10 (16 rows) = 16 B/pair -> 4 MB/CU ->
// 27 us floor (measured 42). v11 (64 rows) = 4 B/pair -> 1.05 MB/CU ->
// ~7 us floor. Pipelined epilogue + deep prefetch were neutral (v10=v9):
// dropped to fund the bigger A-tile within the register budget.
//
// Shape: wave = 64 rows (af[4][4] = 64 VGPR, 4 independent MFMA chains),
// block = 4 waves = 256 rows x 256 cols (TPG=16 col-tiles), grid 32x32 =
// 1024 blocks. amdgpu_waves_per_eu(3,3): 170-reg budget, ~156 live, no
// spill (r7/r8: pin the target; rolled loop; named/const-indexed buffers
// only). Depth-2 prefetch b0/b1. No LDS, no barriers, no in-loop cvt
// (prep emits fragment-ready fp16 + pre-scaled norms; ws-poison fill
// (~43 us) dominates the harness floor per r9 — unavoidable).
//
// Fragment mappings (verified end-to-end rounds 2-10):
//   A: lane holds A[m=lane&15][k=(lane>>4)*8+j]
//   B: lane holds B^T row-major: col=lane&15, k=(lane>>4)*8+j
//   C/D: col=lane&15, row=(lane>>4)*4+reg
// fp16 single-pass accuracy verified r4-r10: absmax 2.8e-17 vs 2.4e-16.

#define D_DIM 128
#define TPG   16   // 16-col tiles per col-group (256 cols) — compile-time

typedef _Float16 f16x8 __attribute__((ext_vector_type(8)));
typedef _Float16 f16x4 __attribute__((ext_vector_type(4)));
typedef __attribute__((ext_vector_type(4))) float f32x4;

#define C2F ((float)(0.5 / 2.50662827463100050242 * 1.44269504088896340736))

// ---- prep: fp32 -> fp16 fragment-major + pre-scaled norms ----------------
// Thread (row, seg 0..31): k = seg*4 -> kc=seg>>3, q=(seg>>1)&3, j0=(seg&1)*4;
// 8 B store at halves offset ((t*4+kc)*64 + q*16 + r)*8 + j0.
__global__ __launch_bounds__(256)
void prep_kernel(const float* __restrict__ x, const float* __restrict__ data,
                 _Float16* __restrict__ xf, _Float16* __restrict__ df,
                 float* __restrict__ xn_u, float* __restrict__ dn_s,
                 int xThreads, float negLogM) {
    const int gid = blockIdx.x * 256 + threadIdx.x;
    const int which = (gid >= xThreads);
    const int id = which ? (gid - xThreads) : gid;
    const int row = id >> 5, seg = id & 31;
    const float* src = which ? data : x;
    _Float16* dst = which ? df : xf;

    const float4 v = *(const float4*)&src[(size_t)row * D_DIM + seg * 4];

    const int t = row >> 4, r = row & 15;
    const int kc = seg >> 3, q = (seg >> 1) & 3, j0 = (seg & 1) * 4;
    f16x4 h;
    h[0] = (_Float16)v.x; h[1] = (_Float16)v.y;
    h[2] = (_Float16)v.z; h[3] = (_Float16)v.w;
    *(f16x4*)&dst[((size_t)(t * 4 + kc) * 64 + q * 16 + r) * 8 + j0] = h;

    float nrm = fmaf(v.x, v.x, fmaf(v.y, v.y, fmaf(v.z, v.z, v.w * v.w)));
#pragma unroll
    for (int off = 1; off < 32; off <<= 1) nrm += __shfl_xor(nrm, off, 64);
    if (seg == 0) {
        if (which) dn_s[row] = -C2F * nrm;
        else       xn_u[row] = fmaf(-C2F, nrm, negLogM);
    }
}

// ---- main: 4 waves x 64 rows, depth-2 prefetch, LDS/barrier-free ---------
__global__ __launch_bounds__(256)
__attribute__((amdgpu_waves_per_eu(3, 3)))
void kde_f16v11(const _Float16* __restrict__ xf, const _Float16* __restrict__ df,
                const float* __restrict__ xn_u, const float* __restrict__ dn_s,
                float* __restrict__ out, int colGroups) {
    const int tid  = threadIdx.x;
    const int lane = tid & 63;
    const int w    = tid >> 6;
    const int q    = lane >> 4;
    const int r    = lane & 15;

    const int bid = blockIdx.x;
    const int cg  = bid % colGroups;
    const int rb  = bid / colGroups;
    const int rowBase  = rb * 256 + w * 64;   // this wave's 64 rows
    const int colTile0 = cg * TPG;

    const float twoC2 = 2.0f * C2F;

    // A fragments: 16 coalesced dwordx4 loads, once (4 row-tiles).
    const int tG0 = rb * 16 + w * 4;
    f16x8 af[4][4];
#pragma unroll
    for (int ri = 0; ri < 4; ++ri)
#pragma unroll
        for (int kc = 0; kc < 4; ++kc)
            af[ri][kc] = *(const f16x8*)&xf[((size_t)((tG0 + ri) * 4 + kc) * 64 + lane) * 8];

    // Row constants (row = q*4+p within each 16-row tile).
    f32x4 u[4];
#pragma unroll
    for (int ri = 0; ri < 4; ++ri)
        u[ri] = *(const f32x4*)&xn_u[rowBase + ri * 16 + q * 4];

    f32x4 srow[4];
#pragma unroll
    for (int ri = 0; ri < 4; ++ri) srow[ri] = (f32x4){0.f, 0.f, 0.f, 0.f};

    const _Float16* dbase = &df[(size_t)colTile0 * 2048];  // 2048 halves/tile
    const float*    nbase = &dn_s[colTile0 * 16 + r];

    // Named depth-2 prefetch buffers (constant indices only; loop rolled).
    f16x8 b0[4], b1[4];
    float dv0, dv1;
#pragma unroll
    for (int kc = 0; kc < 4; ++kc) {
        b0[kc] = *(const f16x8*)&dbase[((size_t)kc * 64 + lane) * 8];
        b1[kc] = *(const f16x8*)&dbase[(size_t)2048 + ((size_t)kc * 64 + lane) * 8];
    }
    dv0 = nbase[0];
    dv1 = nbase[16];

#pragma unroll 1
    for (int it = 0; it < TPG; it += 2) {
        // ---- tile it: compute with b0 ----
        {
            f32x4 a0 = (f32x4){0.f, 0.f, 0.f, 0.f};
            f32x4 a1 = (f32x4){0.f, 0.f, 0.f, 0.f};
            f32x4 a2 = (f32x4){0.f, 0.f, 0.f, 0.f};
            f32x4 a3 = (f32x4){0.f, 0.f, 0.f, 0.f};
#pragma unroll
            for (int kc = 0; kc < 4; ++kc) {
                a0 = __builtin_amdgcn_mfma_f32_16x16x32_f16(af[0][kc], b0[kc], a0, 0, 0, 0);
                a1 = __builtin_amdgcn_mfma_f32_16x16x32_f16(af[1][kc], b0[kc], a1, 0, 0, 0);
                a2 = __builtin_amdgcn_mfma_f32_16x16x32_f16(af[2][kc], b0[kc], a2, 0, 0, 0);
                a3 = __builtin_amdgcn_mfma_f32_16x16x32_f16(af[3][kc], b0[kc], a3, 0, 0, 0);
            }
            // prefetch tile it+2 -> b0 (masked wrap: stays in-group)
            {
                const int t2 = (it + 2) & (TPG - 1);
#pragma unroll
                for (int kc = 0; kc < 4; ++kc)
                    b0[kc] = *(const f16x8*)&dbase[(size_t)t2 * 2048 + ((size_t)kc * 64 + lane) * 8];
            }
#pragma unroll
            for (int ri = 0; ri < 4; ++ri) {
                const f32x4 a = (ri == 0) ? a0 : (ri == 1) ? a1 : (ri == 2) ? a2 : a3;
                srow[ri][0] += __builtin_amdgcn_exp2f(fmaf(twoC2, a[0], u[ri][0] + dv0));
                srow[ri][1] += __builtin_amdgcn_exp2f(fmaf(twoC2, a[1], u[ri][1] + dv0));
                srow[ri][2] += __builtin_amdgcn_exp2f(fmaf(twoC2, a[2], u[ri][2] + dv0));
                srow[ri][3] += __builtin_amdgcn_exp2f(fmaf(twoC2, a[3], u[ri][3] + dv0));
            }
            dv0 = nbase[((it + 2) & (TPG - 1)) * 16];
        }
        // ---- tile it+1: compute with b1 ----
        {
            f32x4 a0 = (f32x4){0.f, 0.f, 0.f, 0.f};
            f32x4 a1 = (f32x4){0.f, 0.f, 0.f, 0.f};
            f32x4 a2 = (f32x4){0.f, 0.f, 0.f, 0.f};
            f32x4 a3 = (f32x4){0.f, 0.f, 0.f, 0.f};
#pragma unroll
            for (int kc = 0; kc < 4; ++kc) {
                a0 = __builtin_amdgcn_mfma_f32_16x16x32_f16(af[0][kc], b1[kc], a0, 0, 0, 0);
                a1 = __builtin_amdgcn_mfma_f32_16x16x32_f16(af[1][kc], b1[kc], a1, 0, 0, 0);
                a2 = __builtin_amdgcn_mfma_f32_16x16x32_f16(af[2][kc], b1[kc], a2, 0, 0, 0);
                a3 = __builtin_amdgcn_mfma_f32_16x16x32_f16(af[3][kc], b1[kc], a3, 0, 0, 0);
            }
            // prefetch tile it+3 -> b1 (masked wrap)
            {
                const int t3 = (it + 3) & (TPG - 1);
#pragma unroll
                for (int kc = 0; kc < 4; ++kc)
                    b1[kc] = *(const f16x8*)&dbase[(size_t)t3 * 2048 + ((size_t)kc * 64 + lane) * 8];
            }
#pragma unroll
            for (int ri = 0; ri < 4; ++ri) {
                const f32x4 a = (ri == 0) ? a0 : (ri == 1) ? a1 : (ri == 2) ? a2 : a3;
                srow[ri][0] += __builtin_amdgcn_exp2f(fmaf(twoC2, a[0], u[ri][0] + dv1));
                srow[ri][1] += __builtin_amdgcn_exp2f(fmaf(twoC2, a[1], u[ri][1] + dv1));
                srow[ri][2] += __builtin_amdgcn_exp2f(fmaf(twoC2, a[2], u[ri][2] + dv1));
                srow[ri][3] += __builtin_amdgcn_exp2f(fmaf(twoC2, a[3], u[ri][3] + dv1));
            }
            dv1 = nbase[((it + 3) & (TPG - 1)) * 16];
        }
    }

    // Reduce srow over the 16 col-lanes (r) and accumulate to out.
#pragma unroll
    for (int ri = 0; ri < 4; ++ri)
#pragma unroll
        for (int p = 0; p < 4; ++p) {
            float s = srow[ri][p];
            s += __shfl_xor(s, 1, 64);
            s += __shfl_xor(s, 2, 64);
            s += __shfl_xor(s, 4, 64);
            s += __shfl_xor(s, 8, 64);
            if (r == 0)
                atomicAdd(&out[rowBase + ri * 16 + q * 4 + p], s);
        }
}

// ---------------- fallback: round-1 VALU kernel (any size, no ws) ---------
#define BN 128
#define BM 128
#define KT 32
#define LDSS 132

__global__ __launch_bounds__(256, 4)
void kde_valu(const float* __restrict__ x, const float* __restrict__ data,
              float* __restrict__ out, int N, int M) {
    __shared__ float xs[KT][LDSS];
    __shared__ float dsh[KT][LDSS];
    __shared__ float xn_s[BN];
    __shared__ float dn_s[BM];
    const int tid = threadIdx.x;
    const int ty = tid >> 4, tx = tid & 15;
    const int rowBase = blockIdx.y * BN, colBase = blockIdx.x * BM;
    float acc[8][8];
#pragma unroll
    for (int i = 0; i < 8; ++i)
#pragma unroll
        for (int j = 0; j < 8; ++j) acc[i][j] = 0.0f;
    float normAcc = 0.0f;
    for (int kc = 0; kc < D_DIM; kc += KT) {
        __syncthreads();
#pragma unroll
        for (int i = 0; i < 4; ++i) {
            const int idx = tid + i * 256;
            const int row = idx >> 3, kq = idx & 7;
            const float4 v = *(const float4*)&x[(size_t)(rowBase + row) * D_DIM + kc + kq * 4];
            xs[kq * 4 + 0][row] = v.x; xs[kq * 4 + 1][row] = v.y;
            xs[kq * 4 + 2][row] = v.z; xs[kq * 4 + 3][row] = v.w;
            const float4 wv = *(const float4*)&data[(size_t)(colBase + row) * D_DIM + kc + kq * 4];
            dsh[kq * 4 + 0][row] = wv.x; dsh[kq * 4 + 1][row] = wv.y;
            dsh[kq * 4 + 2][row] = wv.z; dsh[kq * 4 + 3][row] = wv.w;
        }
        __syncthreads();
        {
            const float* col = (tid < 128) ? &xs[0][tid] : &dsh[0][tid - 128];
#pragma unroll
            for (int k = 0; k < KT; ++k) { const float v = col[k * LDSS]; normAcc = fmaf(v, v, normAcc); }
        }
#pragma unroll
        for (int k = 0; k < KT; ++k) {
            float a[8], b[8];
            *(float4*)&a[0] = *(const float4*)&xs[k][ty * 8];
            *(float4*)&a[4] = *(const float4*)&xs[k][ty * 8 + 4];
            *(float4*)&b[0] = *(const float4*)&dsh[k][tx * 4];
            *(float4*)&b[4] = *(const float4*)&dsh[k][64 + tx * 4];
#pragma unroll
            for (int i = 0; i < 8; ++i)
#pragma unroll
                for (int j = 0; j < 8; ++j) acc[i][j] = fmaf(a[i], b[j], acc[i][j]);
        }
    }
    if (tid < 128) xn_s[tid] = normAcc; else dn_s[tid - 128] = normAcc;
    __syncthreads();
    const float C2 = C2F;
    const float negLogM = -log2f((float)M);
#pragma unroll
    for (int i = 0; i < 8; ++i) {
        const int row = ty * 8 + i;
        const float xnr = xn_s[row];
        float s = 0.0f;
#pragma unroll
        for (int j = 0; j < 8; ++j) {
            const int col = (j < 4) ? (tx * 4 + j) : (64 + tx * 4 + (j - 4));
            const float sq = xnr + dn_s[col] - 2.0f * acc[i][j];
            s += exp2f(fmaf(-C2, sq, negLogM));
        }
#pragma unroll
        for (int off = 1; off < 16; off <<= 1) s += __shfl_xor(s, off, 64);
        if (tx == 0) atomicAdd(&out[rowBase + row], s);
    }
}

extern "C" void kernel_launch(void* const* d_in, const int* in_sizes, int n_in,
                              void* d_out, int out_size, void* d_ws, size_t ws_size,
                              hipStream_t stream) {
    const float* x    = (const float*)d_in[0];
    const float* data = (const float*)d_in[1];
    float* out = (float*)d_out;
    const int N = in_sizes[0] / D_DIM;
    const int M = in_sizes[1] / D_DIM;

    hipMemsetAsync(d_out, 0, (size_t)out_size * sizeof(float), stream);

    const size_t need = (size_t)(N + M) * D_DIM * 2 + (size_t)(N + M) * 4;
    if (ws_size < need || (N & 255) || (M & 255)) {
        dim3 grid(M / BM, N / BN);
        kde_valu<<<grid, 256, 0, stream>>>(x, data, out, N, M);
        return;
    }

    _Float16* xf = (_Float16*)d_ws;
    _Float16* df = xf + (size_t)N * D_DIM;
    float* xn_u = (float*)(df + (size_t)M * D_DIM);
    float* dn_s = xn_u + N;

    const float negLogM = -log2f((float)M);
    const int xThreads = N * 32;
    const int totThreads = (N + M) * 32;
    prep_kernel<<<totThreads / 256, 256, 0, stream>>>(x, data, xf, df, xn_u, dn_s,
                                                      xThreads, negLogM);

    const int colGroups = M / 256;           // 256 cols/group, TPG=16 tiles
    const int rowBlocks = N / 256;
    kde_f16v11<<<rowBlocks * colGroups, 256, 0, stream>>>(xf, df, xn_u, dn_s, out,
                                                          colGroups);
}

// Round 12
// 86.935 us; speedup vs baseline: 1.1360x; 1.0993x over previous
//
#include <hip/hip_runtime.h>
#include <math.h>

// KDE via GEMM trick, v12 = champion v9 + depth-3 prefetch + epilogue mul.
//   density[i] = (1/M) * sum_j exp2(-C2*sq_ij - log2(M))
//   sq_ij = |x_i|^2 + |d_j|^2 - 2*dot(x_i,d_j)
//
// CROSS-ROUND SOLVE (H ~= 56.5 us fixed harness overhead: 42 us ws-poison
// fill + restore/memset/prep/gaps): v9 main ~31 us (best), v10 = 42,
// v11 ~39. v11's loss = generation tail (3 blocks/CU -> 2 gens, x1.33).
// v9's config is the family optimum: wave = 32 rows, block = 4 waves =
// 128 rows x 512 cols, TPG=32, grid 64x16 = 1024 = exactly 4 blocks/CU
// at waves_per_eu(4,4), single generation.
//
// v12 deltas vs v9 (only these):
//  1. TRUE depth-3 B prefetch: named b0/b1/b2, 3 bodies per rolled iter,
//     body computing tile t reloads its buffer for t+3 (v9's effective
//     distance was ~0.5-1 body -> first-touch L3 latency ~600cyc exposed).
//     Masked wrap (&31) keeps reload indices in-group; tiles 30,31 done
//     in a no-reload epilogue.
//  2. exp2(a+dv) = exp2(a)*exp2(dv): 1 exp2(dv) per tile replaces 8 adds,
//     srow = fma(exp2(fma(2C2,acc,u)), edv, srow). Overflow-safe
//     (exp2 arg <= C2*|d|^2 - 13 ~ 2^40 max).
// Registers ~120 < 128 budget (pinned waves_per_eu(4,4); r7/r8 lessons:
// pin target, rolled loop, named const-indexed buffers only).
//
// Fragment mappings (verified end-to-end rounds 2-11):
//   A: lane holds A[m=lane&15][k=(lane>>4)*8+j]
//   B: lane holds B^T row-major: col=lane&15, k=(lane>>4)*8+j
//   C/D: col=lane&15, row=(lane>>4)*4+reg
// fp16 single-pass accuracy verified r4-r11: absmax 2.8e-17 vs 2.4e-16.

#define D_DIM 128
#define TPG   32   // 16-col tiles per col-group (512 cols) — compile-time

typedef _Float16 f16x8 __attribute__((ext_vector_type(8)));
typedef _Float16 f16x4 __attribute__((ext_vector_type(4)));
typedef __attribute__((ext_vector_type(4))) float f32x4;

#define C2F ((float)(0.5 / 2.50662827463100050242 * 1.44269504088896340736))

// ---- prep: fp32 -> fp16 fragment-major + pre-scaled norms ----------------
__global__ __launch_bounds__(256)
void prep_kernel(const float* __restrict__ x, const float* __restrict__ data,
                 _Float16* __restrict__ xf, _Float16* __restrict__ df,
                 float* __restrict__ xn_u, float* __restrict__ dn_s,
                 int xThreads, float negLogM) {
    const int gid = blockIdx.x * 256 + threadIdx.x;
    const int which = (gid >= xThreads);
    const int id = which ? (gid - xThreads) : gid;
    const int row = id >> 5, seg = id & 31;
    const float* src = which ? data : x;
    _Float16* dst = which ? df : xf;

    const float4 v = *(const float4*)&src[(size_t)row * D_DIM + seg * 4];

    const int t = row >> 4, r = row & 15;
    const int kc = seg >> 3, q = (seg >> 1) & 3, j0 = (seg & 1) * 4;
    f16x4 h;
    h[0] = (_Float16)v.x; h[1] = (_Float16)v.y;
    h[2] = (_Float16)v.z; h[3] = (_Float16)v.w;
    *(f16x4*)&dst[((size_t)(t * 4 + kc) * 64 + q * 16 + r) * 8 + j0] = h;

    float nrm = fmaf(v.x, v.x, fmaf(v.y, v.y, fmaf(v.z, v.z, v.w * v.w)));
#pragma unroll
    for (int off = 1; off < 32; off <<= 1) nrm += __shfl_xor(nrm, off, 64);
    if (seg == 0) {
        if (which) dn_s[row] = -C2F * nrm;
        else       xn_u[row] = fmaf(-C2F, nrm, negLogM);
    }
}

// ---- main: 4 waves x 32 rows, depth-3 prefetch, LDS/barrier-free ---------
__global__ __launch_bounds__(256)
__attribute__((amdgpu_waves_per_eu(4, 4)))
void kde_f16v12(const _Float16* __restrict__ xf, const _Float16* __restrict__ df,
                const float* __restrict__ xn_u, const float* __restrict__ dn_s,
                float* __restrict__ out, int colGroups) {
    const int tid  = threadIdx.x;
    const int lane = tid & 63;
    const int w    = tid >> 6;
    const int q    = lane >> 4;
    const int r    = lane & 15;

    const int bid = blockIdx.x;
    const int cg  = bid % colGroups;
    const int rb  = bid / colGroups;
    const int rowBase  = rb * 128 + w * 32;  // this wave's 32 rows
    const int colTile0 = cg * TPG;

    const float twoC2 = 2.0f * C2F;

    // A fragments: 8 coalesced dwordx4 loads, once (2 row-tiles).
    f16x8 af0[4], af1[4];
    {
        const int tG0 = rb * 8 + w * 2;
#pragma unroll
        for (int kc = 0; kc < 4; ++kc) {
            af0[kc] = *(const f16x8*)&xf[((size_t)(tG0 * 4 + kc) * 64 + lane) * 8];
            af1[kc] = *(const f16x8*)&xf[((size_t)((tG0 + 1) * 4 + kc) * 64 + lane) * 8];
        }
    }

    const f32x4 u0 = *(const f32x4*)&xn_u[rowBase + q * 4];
    const f32x4 u1 = *(const f32x4*)&xn_u[rowBase + 16 + q * 4];

    f32x4 srow0 = (f32x4){0.f, 0.f, 0.f, 0.f};
    f32x4 srow1 = (f32x4){0.f, 0.f, 0.f, 0.f};

    const _Float16* dbase = &df[(size_t)colTile0 * 2048];   // 2048 halves/tile
    const float*    nbase = &dn_s[colTile0 * 16 + r];

    // Named depth-3 prefetch buffers (constant indices; loop rolled).
    f16x8 b0[4], b1[4], b2[4];
    float dv0, dv1, dv2;
#pragma unroll
    for (int kc = 0; kc < 4; ++kc) {
        b0[kc] = *(const f16x8*)&dbase[(size_t)0 * 2048 + ((size_t)kc * 64 + lane) * 8];
        b1[kc] = *(const f16x8*)&dbase[(size_t)1 * 2048 + ((size_t)kc * 64 + lane) * 8];
        b2[kc] = *(const f16x8*)&dbase[(size_t)2 * 2048 + ((size_t)kc * 64 + lane) * 8];
    }
    dv0 = nbase[0 * 16];
    dv1 = nbase[1 * 16];
    dv2 = nbase[2 * 16];

    // Body: compute tile with BUF/DVV, reload BUF <- tile RT (masked), then
    // epilogue via exp2-product; finally DVV <- norm of tile RT.
#define BODY(BUF, DVV, RT)                                                        \
    {                                                                             \
        f32x4 a0 = (f32x4){0.f, 0.f, 0.f, 0.f};                                   \
        f32x4 a1 = (f32x4){0.f, 0.f, 0.f, 0.f};                                   \
        _Pragma("unroll")                                                         \
        for (int kc = 0; kc < 4; ++kc) {                                          \
            a0 = __builtin_amdgcn_mfma_f32_16x16x32_f16(af0[kc], BUF[kc], a0, 0, 0, 0); \
            a1 = __builtin_amdgcn_mfma_f32_16x16x32_f16(af1[kc], BUF[kc], a1, 0, 0, 0); \
        }                                                                         \
        const int rt_ = (RT) & (TPG - 1);                                         \
        _Pragma("unroll")                                                         \
        for (int kc = 0; kc < 4; ++kc)                                            \
            BUF[kc] = *(const f16x8*)&dbase[(size_t)rt_ * 2048 + ((size_t)kc * 64 + lane) * 8]; \
        const float edv_ = __builtin_amdgcn_exp2f(DVV);                           \
        srow0[0] = fmaf(__builtin_amdgcn_exp2f(fmaf(twoC2, a0[0], u0[0])), edv_, srow0[0]); \
        srow0[1] = fmaf(__builtin_amdgcn_exp2f(fmaf(twoC2, a0[1], u0[1])), edv_, srow0[1]); \
        srow0[2] = fmaf(__builtin_amdgcn_exp2f(fmaf(twoC2, a0[2], u0[2])), edv_, srow0[2]); \
        srow0[3] = fmaf(__builtin_amdgcn_exp2f(fmaf(twoC2, a0[3], u0[3])), edv_, srow0[3]); \
        srow1[0] = fmaf(__builtin_amdgcn_exp2f(fmaf(twoC2, a1[0], u1[0])), edv_, srow1[0]); \
        srow1[1] = fmaf(__builtin_amdgcn_exp2f(fmaf(twoC2, a1[1], u1[1])), edv_, srow1[1]); \
        srow1[2] = fmaf(__builtin_amdgcn_exp2f(fmaf(twoC2, a1[2], u1[2])), edv_, srow1[2]); \
        srow1[3] = fmaf(__builtin_amdgcn_exp2f(fmaf(twoC2, a1[3], u1[3])), edv_, srow1[3]); \
        DVV = nbase[rt_ * 16];                                                    \
    }

// Final body: no reload, no DV update.
#define BODYF(BUF, DVV)                                                           \
    {                                                                             \
        f32x4 a0 = (f32x4){0.f, 0.f, 0.f, 0.f};                                   \
        f32x4 a1 = (f32x4){0.f, 0.f, 0.f, 0.f};                                   \
        _Pragma("unroll")                                                         \
        for (int kc = 0; kc < 4; ++kc) {                                          \
            a0 = __builtin_amdgcn_mfma_f32_16x16x32_f16(af0[kc], BUF[kc], a0, 0, 0, 0); \
            a1 = __builtin_amdgcn_mfma_f32_16x16x32_f16(af1[kc], BUF[kc], a1, 0, 0, 0); \
        }                                                                         \
        const float edv_ = __builtin_amdgcn_exp2f(DVV);                           \
        srow0[0] = fmaf(__builtin_amdgcn_exp2f(fmaf(twoC2, a0[0], u0[0])), edv_, srow0[0]); \
        srow0[1] = fmaf(__builtin_amdgcn_exp2f(fmaf(twoC2, a0[1], u0[1])), edv_, srow0[1]); \
        srow0[2] = fmaf(__builtin_amdgcn_exp2f(fmaf(twoC2, a0[2], u0[2])), edv_, srow0[2]); \
        srow0[3] = fmaf(__builtin_amdgcn_exp2f(fmaf(twoC2, a0[3], u0[3])), edv_, srow0[3]); \
        srow1[0] = fmaf(__builtin_amdgcn_exp2f(fmaf(twoC2, a1[0], u1[0])), edv_, srow1[0]); \
        srow1[1] = fmaf(__builtin_amdgcn_exp2f(fmaf(twoC2, a1[1], u1[1])), edv_, srow1[1]); \
        srow1[2] = fmaf(__builtin_amdgcn_exp2f(fmaf(twoC2, a1[2], u1[2])), edv_, srow1[2]); \
        srow1[3] = fmaf(__builtin_amdgcn_exp2f(fmaf(twoC2, a1[3], u1[3])), edv_, srow1[3]); \
    }

    // Tiles 0..29 in 10 rolled iterations of 3 bodies; reloads reach t+3.
#pragma unroll 1
    for (int it = 0; it < TPG - 2; it += 3) {
        BODY(b0, dv0, it + 3);
        BODY(b1, dv1, it + 4);
        BODY(b2, dv2, it + 5);
    }
    // Tiles 30, 31 (already resident in b0, b1).
    BODYF(b0, dv0);
    BODYF(b1, dv1);

#undef BODY
#undef BODYF

    // Reduce over the 16 col-lanes (r) and accumulate to out.
#pragma unroll
    for (int p = 0; p < 4; ++p) {
        float s = srow0[p];
        s += __shfl_xor(s, 1, 64);
        s += __shfl_xor(s, 2, 64);
        s += __shfl_xor(s, 4, 64);
        s += __shfl_xor(s, 8, 64);
        if (r == 0) atomicAdd(&out[rowBase + q * 4 + p], s);
        float s1 = srow1[p];
        s1 += __shfl_xor(s1, 1, 64);
        s1 += __shfl_xor(s1, 2, 64);
        s1 += __shfl_xor(s1, 4, 64);
        s1 += __shfl_xor(s1, 8, 64);
        if (r == 0) atomicAdd(&out[rowBase + 16 + q * 4 + p], s1);
    }
}

// ---------------- fallback: round-1 VALU kernel (any size, no ws) ---------
#define BN 128
#define BM 128
#define KT 32
#define LDSS 132

__global__ __launch_bounds__(256, 4)
void kde_valu(const float* __restrict__ x, const float* __restrict__ data,
              float* __restrict__ out, int N, int M) {
    __shared__ float xs[KT][LDSS];
    __shared__ float dsh[KT][LDSS];
    __shared__ float xn_s[BN];
    __shared__ float dn_s[BM];
    const int tid = threadIdx.x;
    const int ty = tid >> 4, tx = tid & 15;
    const int rowBase = blockIdx.y * BN, colBase = blockIdx.x * BM;
    float acc[8][8];
#pragma unroll
    for (int i = 0; i < 8; ++i)
#pragma unroll
        for (int j = 0; j < 8; ++j) acc[i][j] = 0.0f;
    float normAcc = 0.0f;
    for (int kc = 0; kc < D_DIM; kc += KT) {
        __syncthreads();
#pragma unroll
        for (int i = 0; i < 4; ++i) {
            const int idx = tid + i * 256;
            const int row = idx >> 3, kq = idx & 7;
            const float4 v = *(const float4*)&x[(size_t)(rowBase + row) * D_DIM + kc + kq * 4];
            xs[kq * 4 + 0][row] = v.x; xs[kq * 4 + 1][row] = v.y;
            xs[kq * 4 + 2][row] = v.z; xs[kq * 4 + 3][row] = v.w;
            const float4 wv = *(const float4*)&data[(size_t)(colBase + row) * D_DIM + kc + kq * 4];
            dsh[kq * 4 + 0][row] = wv.x; dsh[kq * 4 + 1][row] = wv.y;
            dsh[kq * 4 + 2][row] = wv.z; dsh[kq * 4 + 3][row] = wv.w;
        }
        __syncthreads();
        {
            const float* col = (tid < 128) ? &xs[0][tid] : &dsh[0][tid - 128];
#pragma unroll
            for (int k = 0; k < KT; ++k) { const float v = col[k * LDSS]; normAcc = fmaf(v, v, normAcc); }
        }
#pragma unroll
        for (int k = 0; k < KT; ++k) {
            float a[8], b[8];
            *(float4*)&a[0] = *(const float4*)&xs[k][ty * 8];
            *(float4*)&a[4] = *(const float4*)&xs[k][ty * 8 + 4];
            *(float4*)&b[0] = *(const float4*)&dsh[k][tx * 4];
            *(float4*)&b[4] = *(const float4*)&dsh[k][64 + tx * 4];
#pragma unroll
            for (int i = 0; i < 8; ++i)
#pragma unroll
                for (int j = 0; j < 8; ++j) acc[i][j] = fmaf(a[i], b[j], acc[i][j]);
        }
    }
    if (tid < 128) xn_s[tid] = normAcc; else dn_s[tid - 128] = normAcc;
    __syncthreads();
    const float C2 = C2F;
    const float negLogM = -log2f((float)M);
#pragma unroll
    for (int i = 0; i < 8; ++i) {
        const int row = ty * 8 + i;
        const float xnr = xn_s[row];
        float s = 0.0f;
#pragma unroll
        for (int j = 0; j < 8; ++j) {
            const int col = (j < 4) ? (tx * 4 + j) : (64 + tx * 4 + (j - 4));
            const float sq = xnr + dn_s[col] - 2.0f * acc[i][j];
            s += exp2f(fmaf(-C2, sq, negLogM));
        }
#pragma unroll
        for (int off = 1; off < 16; off <<= 1) s += __shfl_xor(s, off, 64);
        if (tx == 0) atomicAdd(&out[rowBase + row], s);
    }
}

extern "C" void kernel_launch(void* const* d_in, const int* in_sizes, int n_in,
                              void* d_out, int out_size, void* d_ws, size_t ws_size,
                              hipStream_t stream) {
    const float* x    = (const float*)d_in[0];
    const float* data = (const float*)d_in[1];
    float* out = (float*)d_out;
    const int N = in_sizes[0] / D_DIM;
    const int M = in_sizes[1] / D_DIM;

    hipMemsetAsync(d_out, 0, (size_t)out_size * sizeof(float), stream);

    const size_t need = (size_t)(N + M) * D_DIM * 2 + (size_t)(N + M) * 4;
    if (ws_size < need || (N & 127) || (M & 511)) {
        dim3 grid(M / BM, N / BN);
        kde_valu<<<grid, 256, 0, stream>>>(x, data, out, N, M);
        return;
    }

    _Float16* xf = (_Float16*)d_ws;
    _Float16* df = xf + (size_t)N * D_DIM;
    float* xn_u = (float*)(df + (size_t)M * D_DIM);
    float* dn_s = xn_u + N;

    const float negLogM = -log2f((float)M);
    const int xThreads = N * 32;
    const int totThreads = (N + M) * 32;
    prep_kernel<<<totThreads / 256, 256, 0, stream>>>(x, data, xf, df, xn_u, dn_s,
                                                      xThreads, negLogM);

    const int colGroups = M / 512;           // 512 cols/group, TPG=32 tiles
    const int rowBlocks = N / 128;
    kde_f16v12<<<rowBlocks * colGroups, 256, 0, stream>>>(xf, df, xn_u, dn_s, out,
                                                          colGroups);
}

// Round 13
// 84.840 us; speedup vs baseline: 1.1641x; 1.0247x over previous
//
#include <hip/hip_runtime.h>
#include <math.h>

// KDE via GEMM trick, v13 = v12 + LDS-deduplicated B stream.
//   density[i] = (1/M) * sum_j exp2(-C2*sq_ij - log2(M))
//   sq_ij = |x_i|^2 + |d_j|^2 - 2*dot(x_i,d_j)
//
// CROSS-ROUND MODEL (r9-r12, H~56.5us fixed harness: 42us ws-poison fill
// + restore/prep/gaps): main plateaus ~30us. Pipe accounting: VALU ~8us,
// MFMA ~5us, VMEM return ~13.6us (2 MB/CU of B reads, 4 waves redundantly
// streaming the same tiles). Latency-depth (r12) and bytes/pair (r11)
// theories falsified; VMEM-pipe occupancy is the surviving bottleneck.
//
// v13: each B tile enters the CU ONCE per block via global_load_lds
// (wave-split, fire-and-forget), consumed by all 4 waves via ds_read_b128
// (separate LDS pipe). VMEM B-traffic 4x down. Barrier discipline (v5
// lesson): 2 tiles per barrier (16 total), stage issued AFTER the barrier
// so each barrier drains loads issued a full compute phase earlier (v3-
// proven), 4 independent blocks/CU cover the drains.
// Shape (v9/v12 optimum): wave=32 rows, block=128 rows x 512 cols, TPG=32,
// grid 64x16=1024 = exactly 4 blocks/CU at pinned waves_per_eu(4,4),
// single generation. Registers ~95 (<128, no spill per r7/r8 lessons:
// pinned target, rolled loop, named const-indexed buffers).
//
// Fragment mappings (verified end-to-end rounds 2-12):
//   A: lane holds A[m=lane&15][k=(lane>>4)*8+j]
//   B: lane holds B^T row-major: col=lane&15, k=(lane>>4)*8+j
//   C/D: col=lane&15, row=(lane>>4)*4+reg
// global_load_lds: LDS dest = wave-uniform base + lane*16 (verified m104);
// df's fragment-major layout matches exactly.
// fp16 single-pass accuracy verified r4-r12: absmax 2.8e-17 vs 2.4e-16.

#define D_DIM 128
#define TPG   32   // 16-col tiles per col-group (512 cols); 16 pairs

typedef _Float16 f16x8 __attribute__((ext_vector_type(8)));
typedef _Float16 f16x4 __attribute__((ext_vector_type(4)));
typedef __attribute__((ext_vector_type(4))) float f32x4;

#define C2F ((float)(0.5 / 2.50662827463100050242 * 1.44269504088896340736))

// ---- prep: fp32 -> fp16 fragment-major + pre-scaled norms ----------------
__global__ __launch_bounds__(256)
void prep_kernel(const float* __restrict__ x, const float* __restrict__ data,
                 _Float16* __restrict__ xf, _Float16* __restrict__ df,
                 float* __restrict__ xn_u, float* __restrict__ dn_s,
                 int xThreads, float negLogM) {
    const int gid = blockIdx.x * 256 + threadIdx.x;
    const int which = (gid >= xThreads);
    const int id = which ? (gid - xThreads) : gid;
    const int row = id >> 5, seg = id & 31;
    const float* src = which ? data : x;
    _Float16* dst = which ? df : xf;

    const float4 v = *(const float4*)&src[(size_t)row * D_DIM + seg * 4];

    const int t = row >> 4, r = row & 15;
    const int kc = seg >> 3, q = (seg >> 1) & 3, j0 = (seg & 1) * 4;
    f16x4 h;
    h[0] = (_Float16)v.x; h[1] = (_Float16)v.y;
    h[2] = (_Float16)v.z; h[3] = (_Float16)v.w;
    *(f16x4*)&dst[((size_t)(t * 4 + kc) * 64 + q * 16 + r) * 8 + j0] = h;

    float nrm = fmaf(v.x, v.x, fmaf(v.y, v.y, fmaf(v.z, v.z, v.w * v.w)));
#pragma unroll
    for (int off = 1; off < 32; off <<= 1) nrm += __shfl_xor(nrm, off, 64);
    if (seg == 0) {
        if (which) dn_s[row] = -C2F * nrm;
        else       xn_u[row] = fmaf(-C2F, nrm, negLogM);
    }
}

// ---- main: 4 waves x 32 rows, LDS-shared B, 2 tiles per barrier ----------
__global__ __launch_bounds__(256)
__attribute__((amdgpu_waves_per_eu(4, 4)))
void kde_f16v13(const _Float16* __restrict__ xf, const _Float16* __restrict__ df,
                const float* __restrict__ xn_u, const float* __restrict__ dn_s,
                float* __restrict__ out, int colGroups) {
    // Double buffer: each holds a PAIR of 16-col B tiles (2 x 4 KB).
    // Chunk c = m*4+kc (m=member 0/1) lives at sh[buf][c*512 .. +512) halves;
    // fragment (kc,lane) of member m at sh[buf][(m*4+kc)*512 + lane*8].
    __shared__ _Float16 sh[2][4096];

    const int tid  = threadIdx.x;
    const int lane = tid & 63;
    const int w    = tid >> 6;
    const int q    = lane >> 4;
    const int r    = lane & 15;

    const int bid = blockIdx.x;
    const int cg  = bid % colGroups;
    const int rb  = bid / colGroups;
    const int rowBase  = rb * 128 + w * 32;  // this wave's 32 rows
    const int colTile0 = cg * TPG;

    const float twoC2 = 2.0f * C2F;

    // A fragments: 8 coalesced dwordx4 loads, once (2 row-tiles).
    f16x8 af0[4], af1[4];
    {
        const int tG0 = rb * 8 + w * 2;
#pragma unroll
        for (int kc = 0; kc < 4; ++kc) {
            af0[kc] = *(const f16x8*)&xf[((size_t)(tG0 * 4 + kc) * 64 + lane) * 8];
            af1[kc] = *(const f16x8*)&xf[((size_t)((tG0 + 1) * 4 + kc) * 64 + lane) * 8];
        }
    }

    const f32x4 u0 = *(const f32x4*)&xn_u[rowBase + q * 4];
    const f32x4 u1 = *(const f32x4*)&xn_u[rowBase + 16 + q * 4];

    f32x4 srow0 = (f32x4){0.f, 0.f, 0.f, 0.f};
    f32x4 srow1 = (f32x4){0.f, 0.f, 0.f, 0.f};

    const _Float16* dbase = &df[(size_t)colTile0 * 2048];   // 2048 halves/tile
    const float*    nbase = &dn_s[colTile0 * 16 + r];

    // Stage pair p into buffer buf: 8 chunks of 1 KB, 2 per wave.
    // Wave-uniform LDS base + lane*16 (HW scatter) matches df layout.
    auto stagePair = [&](int p, int buf) {
#pragma unroll
        for (int i = 0; i < 2; ++i) {
            const int c  = w * 2 + i;          // 0..7
            const int m  = c >> 2, kc = c & 3;
            const _Float16* g = &dbase[(size_t)(p * 2 + m) * 2048 + (size_t)kc * 512 + (size_t)lane * 8];
            __builtin_amdgcn_global_load_lds(
                (const __attribute__((address_space(1))) void*)g,
                (__attribute__((address_space(3))) void*)&sh[buf][c * 512], 16, 0, 0);
        }
    };

// Compute one 16-col tile (member M of the current pair) from LDS.
#define TILE(BUF, M, DVV)                                                         \
    {                                                                             \
        f16x8 b[4];                                                               \
        _Pragma("unroll")                                                         \
        for (int kc = 0; kc < 4; ++kc)                                            \
            b[kc] = *(const f16x8*)&sh[BUF][((M) * 4 + kc) * 512 + lane * 8];     \
        f32x4 a0 = (f32x4){0.f, 0.f, 0.f, 0.f};                                   \
        f32x4 a1 = (f32x4){0.f, 0.f, 0.f, 0.f};                                   \
        _Pragma("unroll")                                                         \
        for (int kc = 0; kc < 4; ++kc) {                                          \
            a0 = __builtin_amdgcn_mfma_f32_16x16x32_f16(af0[kc], b[kc], a0, 0, 0, 0); \
            a1 = __builtin_amdgcn_mfma_f32_16x16x32_f16(af1[kc], b[kc], a1, 0, 0, 0); \
        }                                                                         \
        const float edv_ = __builtin_amdgcn_exp2f(DVV);                           \
        srow0[0] = fmaf(__builtin_amdgcn_exp2f(fmaf(twoC2, a0[0], u0[0])), edv_, srow0[0]); \
        srow0[1] = fmaf(__builtin_amdgcn_exp2f(fmaf(twoC2, a0[1], u0[1])), edv_, srow0[1]); \
        srow0[2] = fmaf(__builtin_amdgcn_exp2f(fmaf(twoC2, a0[2], u0[2])), edv_, srow0[2]); \
        srow0[3] = fmaf(__builtin_amdgcn_exp2f(fmaf(twoC2, a0[3], u0[3])), edv_, srow0[3]); \
        srow1[0] = fmaf(__builtin_amdgcn_exp2f(fmaf(twoC2, a1[0], u1[0])), edv_, srow1[0]); \
        srow1[1] = fmaf(__builtin_amdgcn_exp2f(fmaf(twoC2, a1[1], u1[1])), edv_, srow1[1]); \
        srow1[2] = fmaf(__builtin_amdgcn_exp2f(fmaf(twoC2, a1[2], u1[2])), edv_, srow1[2]); \
        srow1[3] = fmaf(__builtin_amdgcn_exp2f(fmaf(twoC2, a1[3], u1[3])), edv_, srow1[3]); \
    }

    stagePair(0, 0);

#pragma unroll 1
    for (int p = 0; p < TPG / 2; ++p) {
        const int buf = p & 1;
        __syncthreads();                    // drains stage(p) (issued a full
                                            // compute phase ago) + frees buf^1
        if (p + 1 < TPG / 2) stagePair(p + 1, buf ^ 1);   // in flight across
                                                          // this pair's compute
        const float dv0 = nbase[(p * 2 + 0) * 16];
        const float dv1 = nbase[(p * 2 + 1) * 16];
        TILE(buf, 0, dv0);
        TILE(buf, 1, dv1);
    }

#undef TILE

    // Reduce over the 16 col-lanes (r) and accumulate to out.
#pragma unroll
    for (int p = 0; p < 4; ++p) {
        float s = srow0[p];
        s += __shfl_xor(s, 1, 64);
        s += __shfl_xor(s, 2, 64);
        s += __shfl_xor(s, 4, 64);
        s += __shfl_xor(s, 8, 64);
        if (r == 0) atomicAdd(&out[rowBase + q * 4 + p], s);
        float s1 = srow1[p];
        s1 += __shfl_xor(s1, 1, 64);
        s1 += __shfl_xor(s1, 2, 64);
        s1 += __shfl_xor(s1, 4, 64);
        s1 += __shfl_xor(s1, 8, 64);
        if (r == 0) atomicAdd(&out[rowBase + 16 + q * 4 + p], s1);
    }
}

// ---------------- fallback: round-1 VALU kernel (any size, no ws) ---------
#define BN 128
#define BM 128
#define KT 32
#define LDSS 132

__global__ __launch_bounds__(256, 4)
void kde_valu(const float* __restrict__ x, const float* __restrict__ data,
              float* __restrict__ out, int N, int M) {
    __shared__ float xs[KT][LDSS];
    __shared__ float dsh[KT][LDSS];
    __shared__ float xn_s[BN];
    __shared__ float dn_s[BM];
    const int tid = threadIdx.x;
    const int ty = tid >> 4, tx = tid & 15;
    const int rowBase = blockIdx.y * BN, colBase = blockIdx.x * BM;
    float acc[8][8];
#pragma unroll
    for (int i = 0; i < 8; ++i)
#pragma unroll
        for (int j = 0; j < 8; ++j) acc[i][j] = 0.0f;
    float normAcc = 0.0f;
    for (int kc = 0; kc < D_DIM; kc += KT) {
        __syncthreads();
#pragma unroll
        for (int i = 0; i < 4; ++i) {
            const int idx = tid + i * 256;
            const int row = idx >> 3, kq = idx & 7;
            const float4 v = *(const float4*)&x[(size_t)(rowBase + row) * D_DIM + kc + kq * 4];
            xs[kq * 4 + 0][row] = v.x; xs[kq * 4 + 1][row] = v.y;
            xs[kq * 4 + 2][row] = v.z; xs[kq * 4 + 3][row] = v.w;
            const float4 wv = *(const float4*)&data[(size_t)(colBase + row) * D_DIM + kc + kq * 4];
            dsh[kq * 4 + 0][row] = wv.x; dsh[kq * 4 + 1][row] = wv.y;
            dsh[kq * 4 + 2][row] = wv.z; dsh[kq * 4 + 3][row] = wv.w;
        }
        __syncthreads();
        {
            const float* col = (tid < 128) ? &xs[0][tid] : &dsh[0][tid - 128];
#pragma unroll
            for (int k = 0; k < KT; ++k) { const float v = col[k * LDSS]; normAcc = fmaf(v, v, normAcc); }
        }
#pragma unroll
        for (int k = 0; k < KT; ++k) {
            float a[8], b[8];
            *(float4*)&a[0] = *(const float4*)&xs[k][ty * 8];
            *(float4*)&a[4] = *(const float4*)&xs[k][ty * 8 + 4];
            *(float4*)&b[0] = *(const float4*)&dsh[k][tx * 4];
            *(float4*)&b[4] = *(const float4*)&dsh[k][64 + tx * 4];
#pragma unroll
            for (int i = 0; i < 8; ++i)
#pragma unroll
                for (int j = 0; j < 8; ++j) acc[i][j] = fmaf(a[i], b[j], acc[i][j]);
        }
    }
    if (tid < 128) xn_s[tid] = normAcc; else dn_s[tid - 128] = normAcc;
    __syncthreads();
    const float C2 = C2F;
    const float negLogM = -log2f((float)M);
#pragma unroll
    for (int i = 0; i < 8; ++i) {
        const int row = ty * 8 + i;
        const float xnr = xn_s[row];
        float s = 0.0f;
#pragma unroll
        for (int j = 0; j < 8; ++j) {
            const int col = (j < 4) ? (tx * 4 + j) : (64 + tx * 4 + (j - 4));
            const float sq = xnr + dn_s[col] - 2.0f * acc[i][j];
            s += exp2f(fmaf(-C2, sq, negLogM));
        }
#pragma unroll
        for (int off = 1; off < 16; off <<= 1) s += __shfl_xor(s, off, 64);
        if (tx == 0) atomicAdd(&out[rowBase + row], s);
    }
}

extern "C" void kernel_launch(void* const* d_in, const int* in_sizes, int n_in,
                              void* d_out, int out_size, void* d_ws, size_t ws_size,
                              hipStream_t stream) {
    const float* x    = (const float*)d_in[0];
    const float* data = (const float*)d_in[1];
    float* out = (float*)d_out;
    const int N = in_sizes[0] / D_DIM;
    const int M = in_sizes[1] / D_DIM;

    hipMemsetAsync(d_out, 0, (size_t)out_size * sizeof(float), stream);

    const size_t need = (size_t)(N + M) * D_DIM * 2 + (size_t)(N + M) * 4;
    if (ws_size < need || (N & 127) || (M & 511)) {
        dim3 grid(M / BM, N / BN);
        kde_valu<<<grid, 256, 0, stream>>>(x, data, out, N, M);
        return;
    }

    _Float16* xf = (_Float16*)d_ws;
    _Float16* df = xf + (size_t)N * D_DIM;
    float* xn_u = (float*)(df + (size_t)M * D_DIM);
    float* dn_s = xn_u + N;

    const float negLogM = -log2f((float)M);
    const int xThreads = N * 32;
    const int totThreads = (N + M) * 32;
    prep_kernel<<<totThreads / 256, 256, 0, stream>>>(x, data, xf, df, xn_u, dn_s,
                                                      xThreads, negLogM);

    const int colGroups = M / 512;           // 512 cols/group, TPG=32 tiles
    const int rowBlocks = N / 128;
    kde_f16v13<<<rowBlocks * colGroups, 256, 0, stream>>>(xf, df, xn_u, dn_s, out,
                                                          colGroups);
}